// Round 3
// baseline (130.573 us; speedup 1.0000x reference)
//
#include <hip/hip_runtime.h>
#include <hip/hip_bf16.h>

// Problem constants
#define B_      4
#define C_IN    64
#define H_      64
#define W_      64
#define OUT_CH  128
#define HP_     66          // padded height/width (halo = features(0))
#define CF      576         // K per tap: 9 features * 64 channels, cf = j*64 + c
#define WP_BYTES  (9 * OUT_CH * CF * 2)          // 1,327,104
#define F_BYTES   (B_ * HP_ * HP_ * CF * 2)      // 20,072,448
#define P_OFFSET  (WP_BYTES + F_BYTES)           // 21,399,552 (16B aligned)
#define NSPLIT  6
// partials: 6 groups x (4 b x 128 o x 4096 pix) fp16 = 25,165,824 B

typedef __bf16 bf16x8 __attribute__((ext_vector_type(8)));
typedef float  f32x4  __attribute__((ext_vector_type(4)));
typedef _Float16 half8 __attribute__((ext_vector_type(8)));

// silu + cubic B-spline bases (Cox-de Boor) — identical semantics to round 1/2 (passed).
__device__ __forceinline__ void compute_features(float x, float f[9]) {
    f[0] = x / (1.0f + __expf(-x));
    float g[12];
#pragma unroll
    for (int i = 0; i < 12; ++i) g[i] = (float)(i - 3) * 0.4f - 1.0f;
    float bb[11];
#pragma unroll
    for (int i = 0; i < 11; ++i) bb[i] = (x >= g[i] && x < g[i + 1]) ? 1.0f : 0.0f;
#pragma unroll
    for (int i = 0; i < 10; ++i)
        bb[i] = (x - g[i]) * (1.0f / (g[i + 1] - g[i])) * bb[i]
              + (g[i + 2] - x) * (1.0f / (g[i + 2] - g[i + 1])) * bb[i + 1];
#pragma unroll
    for (int i = 0; i < 9; ++i)
        bb[i] = (x - g[i]) * (1.0f / (g[i + 2] - g[i])) * bb[i]
              + (g[i + 3] - x) * (1.0f / (g[i + 3] - g[i + 1])) * bb[i + 1];
#pragma unroll
    for (int i = 0; i < 8; ++i)
        bb[i] = (x - g[i]) * (1.0f / (g[i + 3] - g[i])) * bb[i]
              + (g[i + 4] - x) * (1.0f / (g[i + 4] - g[i + 1])) * bb[i + 1];
#pragma unroll
    for (int i = 0; i < 8; ++i) f[1 + i] = bb[i];
}

// Kernel 1: pack merged weights -> bf16, Wp[(tap*128 + o)*576 + j*64 + c]
__global__ __launch_bounds__(256) void pack_kernel(
        const float* __restrict__ bw, const float* __restrict__ sw,
        const float* __restrict__ sc, __hip_bfloat16* __restrict__ Wp) {
    int idx = blockIdx.x * 256 + threadIdx.x;          // 0 .. 663551
    if (idx < 589824) {                                 // spline: idx = o*4608 + d*8 + j
        int o = idx / 4608;
        int r = idx - o * 4608;
        int d = r >> 3;
        int j = r & 7;
        int tap = d % 9;
        int c   = d / 9;
        float v = sw[idx] * sc[o * 576 + d];
        Wp[(tap * OUT_CH + o) * CF + (j + 1) * 64 + c] = __float2bfloat16(v);
    } else {                                            // base: k = o*576 + d
        int k = idx - 589824;
        int o = k / 576;
        int d = k - o * 576;
        int tap = d % 9;
        int c   = d / 9;
        Wp[(tap * OUT_CH + o) * CF + c] = __float2bfloat16(bw[k]);
    }
}

// Kernel 2: per-pixel features with halo. F[((b*66+hp)*66+wp)*576 + j*64 + c]
__global__ __launch_bounds__(256) void feat_kernel(
        const float* __restrict__ x, __hip_bfloat16* __restrict__ F) {
    __shared__ float xs[64][65];
    int b  = blockIdx.x / HP_;
    int hp = blockIdx.x % HP_;
    int h  = hp - 1;
    int tid = threadIdx.x;

    float f0[9];
    compute_features(0.0f, f0);

    bool interior_row = (h >= 0) && (h < H_);
    if (interior_row) {
        int wl  = tid & 63;
        int c16 = tid >> 6;
#pragma unroll
        for (int i = 0; i < 16; ++i) {
            int c = c16 * 16 + i;
            xs[c][wl] = x[((b * C_IN + c) * H_ + h) * W_ + wl];
        }
    }
    __syncthreads();

    int c  = tid & 63;
    int wg = tid >> 6;
    __hip_bfloat16* Frow = F + (size_t)((b * HP_ + hp) * HP_) * CF;

    if (!interior_row) {
        for (int wp = wg; wp < HP_; wp += 4) {
            __hip_bfloat16* dst = Frow + (size_t)wp * CF + c;
#pragma unroll
            for (int j = 0; j < 9; ++j) dst[j * 64] = __float2bfloat16(f0[j]);
        }
        return;
    }
    if (wg == 0) {
        __hip_bfloat16* dst = Frow + c;
#pragma unroll
        for (int j = 0; j < 9; ++j) dst[j * 64] = __float2bfloat16(f0[j]);
    }
    if (wg == 3) {
        __hip_bfloat16* dst = Frow + (size_t)65 * CF + c;
#pragma unroll
        for (int j = 0; j < 9; ++j) dst[j * 64] = __float2bfloat16(f0[j]);
    }
    for (int w2 = wg; w2 < 64; w2 += 4) {
        float xv = xs[c][w2];
        float f[9];
        compute_features(xv, f);
        __hip_bfloat16* dst = Frow + (size_t)(w2 + 1) * CF + c;
#pragma unroll
        for (int j = 0; j < 9; ++j) dst[j * 64] = __float2bfloat16(f[j]);
    }
}

// Kernel 3: implicit-GEMM with tap-shared LDS feature footprint.
// Grid = 768 = 6 k-groups x 128 pixel tiles (2 output rows each) = exactly 3/CU.
// Block: 128 o x 128 pix. K-units u = kc*2+h32 (18 of 32-k each); group owns 3 units;
// per unit: stage footprint [4 rows][68 wp][32 k] ONCE, then 9 taps read shifted
// windows. Weights Bs [128 o][32 k] double-buffered per (unit,tap) step.
// XOR-swizzled 16B granules; staging via global_load_lds dwordx4 (lane-contiguous LDS).
__global__ __launch_bounds__(256, 3) void gemm_kernel(
        const __hip_bfloat16* __restrict__ Fb, const __hip_bfloat16* __restrict__ Wpb,
        _Float16* __restrict__ P) {
    // Fs granule (row,wp,c4) at slot (row*68+wp)*4 + (c4 ^ ((wp>>1)&3)); 1088 slots/buf
    // Bs granule (o,c4)      at slot o*4        + (c4 ^ ((o >>1)&3));  512 slots/buf
    __shared__ __align__(16) ushort Fs[2][1088 * 8];   // 34,816 B
    __shared__ __align__(16) ushort Bs[2][512 * 8];    // 16,384 B

    const ushort* F  = (const ushort*)Fb;
    const ushort* Wp = (const ushort*)Wpb;

    int tid  = threadIdx.x;
    int lane = tid & 63;
    int w    = tid >> 6;
    int l15  = lane & 15;
    int lq   = lane >> 4;                // granule c4 for frag reads
    int wm   = w & 1;                    // out_ch half
    int wn   = w >> 1;                   // pixel half

    int blk = blockIdx.x;
    int ug  = blk >> 7;                  // k-group 0..5
    int t   = blk & 127;
    int b   = t >> 5;
    int ho0 = (t & 31) << 1;             // 2 output rows
    int u0  = ug * 3;                    // first k-unit

    f32x4 acc[4][4];
#pragma unroll
    for (int i = 0; i < 4; ++i)
#pragma unroll
        for (int j = 0; j < 4; ++j) acc[i][j] = (f32x4){0.f, 0.f, 0.f, 0.f};

    // ---- stage weights chunk for (u, tap) into Bs[buf]: 512 slots, 2/thread ----
    auto stage_b = [&](int u, int tap, int buf) {
        int kc  = u >> 1;
        int h32 = u & 1;
        const ushort* base = Wp + (size_t)(tap * OUT_CH) * CF + kc * 64 + h32 * 32;
#pragma unroll
        for (int i = 0; i < 2; ++i) {
            int sb   = (w * 2 + i) * 64;          // wave-uniform slot base
            int slot = sb + lane;
            int o  = slot >> 2;
            int c4 = (slot & 3) ^ ((o >> 1) & 3);
            const ushort* src = base + (size_t)o * CF + c4 * 8;
            __builtin_amdgcn_global_load_lds(
                (const __attribute__((address_space(1))) unsigned int*)src,
                (__attribute__((address_space(3))) unsigned int*)&Bs[buf][sb * 8],
                16, 0, 0);
        }
    };

    // ---- stage feature footprint for unit u into Fs[buf]: 1088 slots, 17 chunks ----
    auto stage_fp = [&](int u, int buf) {
        int kc  = u >> 1;
        int h32 = u & 1;
        const ushort* base = F + (size_t)((b * HP_ + ho0) * HP_) * CF + kc * 64 + h32 * 32;
#pragma unroll
        for (int i = 0; i < 5; ++i) {
            int ch = w + 4 * i;
            if (ch >= 17) break;
            int sb   = ch * 64;
            int slot = sb + lane;
            int q   = slot >> 2;                  // row*68 + wp
            int row = q / 68;
            int wp  = q - row * 68;
            if (wp > 65) wp = 65;                 // pad lanes: harmless dup load
            int c4 = (slot & 3) ^ ((wp >> 1) & 3);
            const ushort* src = base + ((size_t)row * HP_ + wp) * CF + c4 * 8;
            __builtin_amdgcn_global_load_lds(
                (const __attribute__((address_space(1))) unsigned int*)src,
                (__attribute__((address_space(3))) unsigned int*)&Fs[buf][sb * 8],
                16, 0, 0);
        }
    };

    stage_fp(u0, 0);
    stage_b(u0, 0, 0);
    int fpb = 0, bb = 0;

    for (int uu = 0; uu < 3; ++uu) {
        int u = u0 + uu;
#pragma unroll
        for (int tap = 0; tap < 9; ++tap) {
            int kh = tap / 3;
            int kw = tap - kh * 3;
            __syncthreads();                       // prev prefetches landed; bufs free
            if (tap < 8) {
                stage_b(u, tap + 1, bb ^ 1);
            } else if (uu < 2) {
                stage_b(u + 1, 0, bb ^ 1);
                stage_fp(u + 1, fpb ^ 1);
            }
            bf16x8 af[4], bq[4];
#pragma unroll
            for (int mt = 0; mt < 4; ++mt) {
                int o    = wm * 64 + mt * 16 + l15;
                int slot = o * 4 + (lq ^ ((o >> 1) & 3));
                af[mt] = *(const bf16x8*)&Bs[bb][slot * 8];
            }
#pragma unroll
            for (int nt = 0; nt < 4; ++nt) {
                int p    = wn * 64 + nt * 16 + l15;
                int fr   = (p >> 6) + kh;
                int wp   = (p & 63) + kw;
                int slot = (fr * 68 + wp) * 4 + (lq ^ ((wp >> 1) & 3));
                bq[nt] = *(const bf16x8*)&Fs[fpb][slot * 8];
            }
#pragma unroll
            for (int mt = 0; mt < 4; ++mt)
#pragma unroll
                for (int nt = 0; nt < 4; ++nt)
                    acc[mt][nt] = __builtin_amdgcn_mfma_f32_16x16x32_bf16(
                        af[mt], bq[nt], acc[mt][nt], 0, 0, 0);
            bb ^= 1;
        }
        fpb ^= 1;
    }

    // epilogue: fp16 partials. P[((ug*4+b)*128 + o)*4096 + ho0*64 + pix]
    _Float16* Pg = P + ((size_t)(ug * 4 + b) * OUT_CH) * 4096 + ho0 * 64;
#pragma unroll
    for (int mt = 0; mt < 4; ++mt) {
        int o = wm * 64 + mt * 16 + (lane >> 4) * 4;
#pragma unroll
        for (int nt = 0; nt < 4; ++nt) {
            int pix = wn * 64 + nt * 16 + l15;
            _Float16* dst = Pg + (size_t)o * 4096 + pix;
#pragma unroll
            for (int r = 0; r < 4; ++r)
                dst[(size_t)r * 4096] = (_Float16)acc[mt][nt][r];
        }
    }
}

// Kernel 4: reduce 6 fp16 partials -> fp32 out. Coalesced half8/float4.
__global__ __launch_bounds__(256) void reduce_kernel(
        const half8* __restrict__ P, float4* __restrict__ out) {
    const int GS = 262144;                    // half8 per group (4*128*4096/8)
    int i = blockIdx.x * 256 + threadIdx.x;
    half8 s[NSPLIT];
#pragma unroll
    for (int g = 0; g < NSPLIT; ++g) s[g] = P[g * GS + i];
    float4 o0, o1;
#pragma unroll
    for (int j = 0; j < 4; ++j) {
        float a = 0.f, bsum = 0.f;
#pragma unroll
        for (int g = 0; g < NSPLIT; ++g) { a += (float)s[g][j]; bsum += (float)s[g][4 + j]; }
        ((float*)&o0)[j] = a;
        ((float*)&o1)[j] = bsum;
    }
    out[i * 2]     = o0;
    out[i * 2 + 1] = o1;
}

extern "C" void kernel_launch(void* const* d_in, const int* in_sizes, int n_in,
                              void* d_out, int out_size, void* d_ws, size_t ws_size,
                              hipStream_t stream) {
    const float* x  = (const float*)d_in[0];   // (4,64,64,64)
    const float* bw = (const float*)d_in[1];   // (128,576)
    const float* sw = (const float*)d_in[2];   // (128,576,8)
    const float* sc = (const float*)d_in[3];   // (128,576)
    float* out = (float*)d_out;                // (4,128,64,64) fp32

    __hip_bfloat16* Wp = (__hip_bfloat16*)d_ws;
    __hip_bfloat16* F  = (__hip_bfloat16*)((char*)d_ws + WP_BYTES);
    _Float16*       P  = (_Float16*)((char*)d_ws + P_OFFSET);

    pack_kernel<<<2592, 256, 0, stream>>>(bw, sw, sc, Wp);
    feat_kernel<<<B_ * HP_, 256, 0, stream>>>(x, F);
    gemm_kernel<<<768, 256, 0, stream>>>(F, Wp, P);
    reduce_kernel<<<1024, 256, 0, stream>>>((const half8*)P, (float4*)out);
}